// Round 11
// baseline (897.335 us; speedup 1.0000x reference)
//
#include <hip/hip_runtime.h>
#include <math.h>

#define EPS_C 1e-4f
#define BMA   128
#define HBLK  262144     // 128 rows * 1024 cols * 2 B (full h block)
#define HHALF 131072     // pass-0 half written to global

typedef __attribute__((ext_vector_type(8)))  __bf16 bf16x8;
typedef __attribute__((ext_vector_type(4)))  float  f32x4;
typedef __attribute__((ext_vector_type(16))) float  f32x16;

#define MFMA16(a, b, c) __builtin_amdgcn_mfma_f32_16x16x32_bf16(a, b, c, 0, 0, 0)
#define MFMA32(a, b, c) __builtin_amdgcn_mfma_f32_32x32x16_bf16(a, b, c, 0, 0, 0)

// packed bf16 convert: D[15:0]=bf16(a), D[31:16]=bf16(b), RNE (gfx950 HW op)
static __device__ __forceinline__ unsigned cvtpk(float a, float b) {
    unsigned r;
    asm("v_cvt_pk_bf16_f32 %0, %1, %2" : "=v"(r) : "v"(a), "v"(b));
    return r;
}

static __device__ __forceinline__ uint4 pack8(const float* v) {
    uint4 p;
    p.x = cvtpk(v[0], v[1]);
    p.y = cvtpk(v[2], v[3]);
    p.z = cvtpk(v[4], v[5]);
    p.w = cvtpk(v[6], v[7]);
    return p;
}

static __device__ __forceinline__ uint4 pack8v(f32x4 lo, f32x4 hi) {
    uint4 p;
    p.x = cvtpk(lo[0], lo[1]);
    p.y = cvtpk(lo[2], lo[3]);
    p.z = cvtpk(hi[0], hi[1]);
    p.w = cvtpk(hi[2], hi[3]);
    return p;
}

// tanh-form GELU via sigmoid: g = v * sigmoid(c1*v + c3*v^3), max err ~1e-3
static __device__ __forceinline__ float gelu_f(float v) {
    const float t = -v * (1.5957691216f + 0.0713548163f * v * v);
    return v / (1.0f + __expf(t));
}

// ============ prep: pack W1 (32x32 B-frags, k-permuted rows) and W2 (16x16 B-frags) ============
// (byte-identical to the round-10 verified prep kernel)
__global__ void prep_kernel(const float* __restrict__ W1, const float* __restrict__ W2,
                            unsigned short* __restrict__ w1p, unsigned short* __restrict__ w2p) {
    const int tid  = blockIdx.x * 256 + threadIdx.x;
    const int frag = tid >> 6;
    if (frag >= 3328) return;
    const int lane = tid & 63;
    if (frag < 2304) {
        const int kt   = frag >> 5;
        const int nt32 = frag & 31;
        const int k0   = kt * 16 + ((lane >> 5) << 3);
        const int n    = nt32 * 32 + (lane & 31);
        float v[8];
#pragma unroll
        for (int i = 0; i < 8; ++i) {
            int kp = k0 + i, ko = kp;
            if (kp >= 128 && kp < 512) { const int q = kp - 128; ko = 128 + (q & 127) * 3 + (q >> 7); }
            v[i] = W1[(size_t)ko * 1024 + n];
        }
        *reinterpret_cast<uint4*>(w1p + (size_t)frag * 512 + lane * 8) = pack8(v);
    } else {
        const int fl = frag - 2304;
        const int kt = fl >> 5;
        const int nt = fl & 31;
        const int k0 = kt * 32 + ((lane >> 4) << 3);
        const int n  = nt * 16 + (lane & 15);
        float v[8];
#pragma unroll
        for (int i = 0; i < 8; ++i) v[i] = W2[(size_t)(k0 + i) * 512 + n];
        *reinterpret_cast<uint4*>(w2p + (size_t)fl * 512 + lane * 8) = pack8(v);
    }
}

// ===================== fused BM=128: panel-streamed x1, 2-N-pass GEMM1, h half round-trip =====================
__global__ __launch_bounds__(1024, 4)
void fused_kernel(const float* __restrict__ x, const float* __restrict__ rot,
                  const float* __restrict__ extra,
                  const float* __restrict__ b1, const float* __restrict__ b2,
                  const char* __restrict__ w1pc, const bf16x8* __restrict__ w2p,
                  char* __restrict__ hmain, char* __restrict__ hspill,
                  long long out_bytes, float* __restrict__ out, int nrows) {
    // pool layout (ushorts): [0,16384) pan0 | [16384,32768) pan1 | [0,65536) stage (lifetime-disjoint)
    //                        [65536,73728) gemm2 DMA panels (2 x 4096)
    __shared__ __align__(16) unsigned short pool[73728];   // 147456 B
    __shared__ float R_s[BMA * 9];                         // 4608 B

    const int tid  = threadIdx.x;
    const int bid  = blockIdx.x;
    const int row0 = bid * BMA;
    const int w    = tid >> 6;   // wave 0..15
    const int lane = tid & 63;
    const int l31  = lane & 31;

    char* hb = (((long long)(bid + 1) * HBLK) <= out_bytes)
             ? (hmain + (size_t)bid * HBLK) : hspill;

    unsigned short* const pan0 = pool;
    unsigned short* const pan1 = pool + 16384;
    unsigned short* const stg  = pool;
    unsigned short* const Pb   = pool + 65536;

    // ---------------- R_s ----------------
    for (int t = tid; t < BMA * 9; t += 1024) {
        int idx = row0 * 9 + t;
        if (idx > nrows * 9 - 1) idx = nrows * 9 - 1;
        R_s[t] = rot[idx];
    }
    __syncthreads();

    // ---------------- build mapping: thread (row bm, col-slice bo of 16) ----------------
    const int bm  = tid >> 3;       // row 0..127
    const int bo  = tid & 7;        // 16-col slice
    const int bmt = bm >> 5;        // mt32 0..3
    int bi = row0 + bm; if (bi > nrows - 1) bi = nrows - 1;
    const float* xrow = x + (size_t)bi * 512;
    const float* erow = extra + (size_t)bi * 512;

    // build panel c (k in [128c, 128c+128)) into bp
    auto BUILD = [&](int c, unsigned short* bp) {
#pragma unroll
        for (int hh = 0; hh < 2; ++hh) {
            const int f0  = bo * 16 + hh * 8;
            const int k   = c * 128 + f0;
            const int ktl = (k >> 4) & 7;
            const int hi  = (k >> 3) & 1;
            uint4 pv;
            if (c == 0) {
                f32x4 a = *reinterpret_cast<const f32x4*>(xrow + f0);
                f32x4 b = *reinterpret_cast<const f32x4*>(xrow + f0 + 4);
                pv = pack8v(a, b);
            } else if (c <= 4) {
                f32x4 xa0 = *reinterpret_cast<const f32x4*>(xrow + 128 + f0);
                f32x4 xa1 = *reinterpret_cast<const f32x4*>(xrow + 128 + f0 + 4);
                f32x4 xb0 = *reinterpret_cast<const f32x4*>(xrow + 256 + f0);
                f32x4 xb1 = *reinterpret_cast<const f32x4*>(xrow + 256 + f0 + 4);
                f32x4 xc0 = *reinterpret_cast<const f32x4*>(xrow + 384 + f0);
                f32x4 xc1 = *reinterpret_cast<const f32x4*>(xrow + 384 + f0 + 4);
                float vv[8];
                if (c <= 3) {
                    const int kk = c - 1;
                    const float r0 = R_s[bm * 9 + kk];
                    const float r1 = R_s[bm * 9 + 3 + kk];
                    const float r2 = R_s[bm * 9 + 6 + kk];
#pragma unroll
                    for (int j = 0; j < 8; ++j) {
                        const float A = (j < 4) ? xa0[j] : xa1[j - 4];
                        const float B = (j < 4) ? xb0[j] : xb1[j - 4];
                        const float C = (j < 4) ? xc0[j] : xc1[j - 4];
                        vv[j] = A * r0 + B * r1 + C * r2;
                    }
                } else {
#pragma unroll
                    for (int j = 0; j < 8; ++j) {
                        const float A = (j < 4) ? xa0[j] : xa1[j - 4];
                        const float B = (j < 4) ? xb0[j] : xb1[j - 4];
                        const float C = (j < 4) ? xc0[j] : xc1[j - 4];
                        vv[j] = sqrtf(A * A + B * B + C * C + EPS_C);
                    }
                }
                pv = pack8(vv);
            } else {
                f32x4 a = *reinterpret_cast<const f32x4*>(erow + (c - 5) * 128 + f0);
                f32x4 b = *reinterpret_cast<const f32x4*>(erow + (c - 5) * 128 + f0 + 4);
                pv = pack8v(a, b);
            }
            *reinterpret_cast<uint4*>(bp + (ktl * 4 + bmt) * 512 + (((bm & 31) + 32 * hi) << 3)) = pv;
        }
    };

    const int hi5 = lane >> 5;
    const int cz  = l31 >> 3;
    const int i7  = lane & 7;

    // ================= GEMM1: two N-half passes =================
#pragma unroll
    for (int p = 0; p < 2; ++p) {
        BUILD(0, pan0);
        const float bw1 = b1[(p * 16 + w) * 32 + l31];

        f32x16 ac0, ac1, ac2, ac3;
#pragma unroll
        for (int z = 0; z < 16; ++z) { ac0[z] = 0.f; ac1[z] = 0.f; ac2[z] = 0.f; ac3[z] = 0.f; }

        const char* wb = w1pc + ((size_t)(p * 16 + w)) * 1024 + lane * 16;   // frag (kt,nt) at (kt*32+nt)*1024
        __syncthreads();   // panel 0 ready

#pragma unroll
        for (int c = 0; c < 9; ++c) {
            unsigned short* rp = (c & 1) ? pan1 : pan0;
            bf16x8 W[4];
#pragma unroll
            for (int t = 0; t < 4; ++t)
                W[t] = *reinterpret_cast<const bf16x8*>(wb + (size_t)(c * 8 + t) * 32768);
            if (c < 8) BUILD(c + 1, (c & 1) ? pan0 : pan1);
            // ktl 0..3
#pragma unroll
            for (int t = 0; t < 4; ++t) {
                const unsigned short* ap = rp + t * 2048 + lane * 8;
                const bf16x8 A0 = *reinterpret_cast<const bf16x8*>(ap);
                const bf16x8 A1 = *reinterpret_cast<const bf16x8*>(ap + 512);
                const bf16x8 A2 = *reinterpret_cast<const bf16x8*>(ap + 1024);
                const bf16x8 A3 = *reinterpret_cast<const bf16x8*>(ap + 1536);
                __builtin_amdgcn_s_setprio(1);
                ac0 = MFMA32(A0, W[t], ac0);
                ac1 = MFMA32(A1, W[t], ac1);
                ac2 = MFMA32(A2, W[t], ac2);
                ac3 = MFMA32(A3, W[t], ac3);
                __builtin_amdgcn_s_setprio(0);
            }
            // ktl 4..7
#pragma unroll
            for (int t = 0; t < 4; ++t)
                W[t] = *reinterpret_cast<const bf16x8*>(wb + (size_t)(c * 8 + 4 + t) * 32768);
#pragma unroll
            for (int t = 0; t < 4; ++t) {
                const unsigned short* ap = rp + (4 + t) * 2048 + lane * 8;
                const bf16x8 A0 = *reinterpret_cast<const bf16x8*>(ap);
                const bf16x8 A1 = *reinterpret_cast<const bf16x8*>(ap + 512);
                const bf16x8 A2 = *reinterpret_cast<const bf16x8*>(ap + 1024);
                const bf16x8 A3 = *reinterpret_cast<const bf16x8*>(ap + 1536);
                __builtin_amdgcn_s_setprio(1);
                ac0 = MFMA32(A0, W[t], ac0);
                ac1 = MFMA32(A1, W[t], ac1);
                ac2 = MFMA32(A2, W[t], ac2);
                ac3 = MFMA32(A3, W[t], ac3);
                __builtin_amdgcn_s_setprio(0);
            }
            __syncthreads();
        }

        // bias + GELU -> stage (16x16 A-frag layout, pass-local [16 ktn][8 mt16][512])
        auto GEL = [&](const f32x16& A, int mt) {
#pragma unroll
            for (int q = 0; q < 8; ++q) {
                const int reg  = 2 * q;
                const int mt16 = mt * 2 + (reg >> 3);
                const int rlo  = (reg & 3) + 8 * ((reg >> 2) & 1) + 4 * hi5;
                const unsigned pr = cvtpk(gelu_f(A[reg] + bw1), gelu_f(A[reg + 1] + bw1));
                unsigned short* pp = &stg[(w * 8 + mt16) * 512 + (rlo + 16 * cz) * 8 + i7];
                pp[0] = (unsigned short)pr;
                pp[8] = (unsigned short)(pr >> 16);
            }
        };
        GEL(ac0, 0); GEL(ac1, 1); GEL(ac2, 2); GEL(ac3, 3);
        __syncthreads();

        if (p == 0) {   // pass-0 h half -> global (coalesced); pass-1 half stays in stage
            const uint4* s4 = reinterpret_cast<const uint4*>(stg);
            uint4* d4 = reinterpret_cast<uint4*>(hb);
#pragma unroll
            for (int q = 0; q < 8; ++q) d4[tid + q * 1024] = s4[tid + q * 1024];
            __syncthreads();
        }
    }

    // ================= GEMM2 (16x16x32): wave (rh = w>>3, g = w&7); nt = {g,g+8,g+16,g+24} =================
    const int rh = w >> 3;
    const int g  = w & 7;
    const int lr = lane & 15;
    const int lk = lane >> 4;

    f32x4 acc2[4][4];
#pragma unroll
    for (int mtl = 0; mtl < 4; ++mtl)
#pragma unroll
        for (int q = 0; q < 4; ++q) acc2[mtl][q] = (f32x4){0.f, 0.f, 0.f, 0.f};

    {
        const bf16x8* wb2 = w2p + (size_t)g * 64 + lane;
        auto LB2 = [&](bf16x8 (&C)[4], int kt2) {
#pragma unroll
            for (int q = 0; q < 4; ++q) C[q] = wb2[(size_t)kt2 * 2048 + q * 512];
        };
        auto DMA = [&](int k2) {
            __builtin_amdgcn_global_load_lds(
                (const __attribute__((address_space(1))) unsigned int*)(hb + k2 * 8192 + w * 1024 + lane * 16),
                (__attribute__((address_space(3))) unsigned int*)(Pb + (k2 & 1) * 4096 + w * 512),
                16, 0, 0);
        };
        auto STEP = [&](bf16x8 (&Cc)[4], bf16x8 (&Cn)[4], int kt2) {
            if (kt2 + 1 < 16 && w < 8) DMA(kt2 + 1);
            if (kt2 + 1 < 32) LB2(Cn, kt2 + 1);
            const unsigned short* ab =
                ((kt2 < 16) ? (Pb + (kt2 & 1) * 4096) : (stg + (kt2 - 16) * 4096))
                + rh * 4 * 512 + lane * 8;
            __builtin_amdgcn_s_setprio(1);
#pragma unroll
            for (int mtl = 0; mtl < 4; ++mtl) {
                const bf16x8 A = *reinterpret_cast<const bf16x8*>(ab + mtl * 512);
#pragma unroll
                for (int q = 0; q < 4; ++q)
                    acc2[mtl][q] = MFMA16(A, Cc[q], acc2[mtl][q]);
            }
            __builtin_amdgcn_s_setprio(0);
            if (kt2 < 15) __syncthreads();
        };

        bf16x8 C0[4], C1[4];
        LB2(C0, 0);
        if (w < 8) DMA(0);
        __syncthreads();
#pragma unroll
        for (int k2 = 0; k2 < 32; k2 += 2) {
            STEP(C0, C1, k2);
            STEP(C1, C0, k2 + 1);
        }
    }

    // ================= epilogue: in-register rotation + store =================
    {
        float bv2[4];
#pragma unroll
        for (int q = 0; q < 4; ++q) bv2[q] = b2[q * 128 + g * 16 + lr];
        const int fcol = g * 16 + lr;
#pragma unroll
        for (int mtl = 0; mtl < 4; ++mtl) {
#pragma unroll
            for (int j = 0; j < 4; ++j) {
                const int rl = rh * 64 + mtl * 16 + lk * 4 + j;
                if (row0 + rl < nrows) {
                    const float* Rp = R_s + rl * 9;
                    const float y0 = acc2[mtl][0][j] + bv2[0];
                    const float y1 = acc2[mtl][1][j] + bv2[1];
                    const float y2 = acc2[mtl][2][j] + bv2[2];
                    const float y3 = acc2[mtl][3][j] + bv2[3];
                    float* op = out + (size_t)(row0 + rl) * 512 + fcol;
                    op[0]   = y0;
                    op[128] = Rp[0] * y1 + Rp[1] * y2 + Rp[2] * y3;
                    op[256] = Rp[3] * y1 + Rp[4] * y2 + Rp[5] * y3;
                    op[384] = Rp[6] * y1 + Rp[7] * y2 + Rp[8] * y3;
                }
            }
        }
    }
}

extern "C" void kernel_launch(void* const* d_in, const int* in_sizes, int n_in,
                              void* d_out, int out_size, void* d_ws, size_t ws_size,
                              hipStream_t stream) {
    const float* x     = (const float*)d_in[0];
    const float* rot   = (const float*)d_in[1];
    const float* extra = (const float*)d_in[2];
    const float* W1    = (const float*)d_in[3];
    const float* b1    = (const float*)d_in[4];
    const float* W2    = (const float*)d_in[5];
    const float* b2    = (const float*)d_in[6];
    float* out = (float*)d_out;

    const int nrows = in_sizes[0] / 512;
    const int nblk  = (nrows + BMA - 1) / BMA;

    // ws: W1 packed (2304 KB) | W2 packed (1024 KB) | tail-block h spill (128 KB)
    unsigned short* w1p = (unsigned short*)d_ws;
    unsigned short* w2p = (unsigned short*)((char*)d_ws + (size_t)2304 * 1024);
    char* hspill        = (char*)d_ws + (size_t)3328 * 1024;

    const long long out_bytes = (long long)out_size * 4;

    prep_kernel<<<(3328 * 64 + 255) / 256, 256, 0, stream>>>(W1, W2, w1p, w2p);

    fused_kernel<<<nblk, 1024, 0, stream>>>(x, rot, extra, b1, b2,
                                            (const char*)w1p, (const bf16x8*)w2p,
                                            (char*)d_out, hspill, out_bytes,
                                            out, nrows);
}

// Round 12
// 727.722 us; speedup vs baseline: 1.2331x; 1.2331x over previous
//
#include <hip/hip_runtime.h>
#include <math.h>

#define EPS_C 1e-4f

typedef __attribute__((ext_vector_type(8)))  __bf16 bf16x8;
typedef __attribute__((ext_vector_type(4)))  float  f32x4;
typedef __attribute__((ext_vector_type(16))) float  f32x16;

#define MFMA16(a, b, c) __builtin_amdgcn_mfma_f32_16x16x32_bf16(a, b, c, 0, 0, 0)
#define MFMA32(a, b, c) __builtin_amdgcn_mfma_f32_32x32x16_bf16(a, b, c, 0, 0, 0)

static __device__ __forceinline__ unsigned cvtpk(float a, float b) {
    unsigned r;
    asm("v_cvt_pk_bf16_f32 %0, %1, %2" : "=v"(r) : "v"(a), "v"(b));
    return r;
}

static __device__ __forceinline__ uint4 pack8(const float* v) {
    uint4 p;
    p.x = cvtpk(v[0], v[1]); p.y = cvtpk(v[2], v[3]);
    p.z = cvtpk(v[4], v[5]); p.w = cvtpk(v[6], v[7]);
    return p;
}

static __device__ __forceinline__ uint4 pack8v(f32x4 lo, f32x4 hi) {
    uint4 p;
    p.x = cvtpk(lo[0], lo[1]); p.y = cvtpk(lo[2], lo[3]);
    p.z = cvtpk(hi[0], hi[1]); p.w = cvtpk(hi[2], hi[3]);
    return p;
}

static __device__ __forceinline__ float gelu_f(float v) {
    const float t = -v * (1.5957691216f + 0.0713548163f * v * v);
    return v / (1.0f + __expf(t));
}

// ============ prep: pack W1 (32x32 B-frags, k-permuted rows) and W2 (16x16 B-frags) ============
__global__ void prep_kernel(const float* __restrict__ W1, const float* __restrict__ W2,
                            unsigned short* __restrict__ w1p, unsigned short* __restrict__ w2p) {
    const int tid  = blockIdx.x * 256 + threadIdx.x;
    const int frag = tid >> 6;
    if (frag >= 3328) return;
    const int lane = tid & 63;
    if (frag < 2304) {
        const int kt   = frag >> 5;
        const int nt32 = frag & 31;
        const int k0   = kt * 16 + ((lane >> 5) << 3);
        const int n    = nt32 * 32 + (lane & 31);
        float v[8];
#pragma unroll
        for (int i = 0; i < 8; ++i) {
            int kp = k0 + i, ko = kp;
            if (kp >= 128 && kp < 512) { const int q = kp - 128; ko = 128 + (q & 127) * 3 + (q >> 7); }
            v[i] = W1[(size_t)ko * 1024 + n];
        }
        *reinterpret_cast<uint4*>(w1p + (size_t)frag * 512 + lane * 8) = pack8(v);
    } else {
        const int fl = frag - 2304;
        const int kt = fl >> 5;
        const int nt = fl & 31;
        const int k0 = kt * 32 + ((lane >> 4) << 3);
        const int n  = nt * 16 + (lane & 15);
        float v[8];
#pragma unroll
        for (int i = 0; i < 8; ++i) v[i] = W2[(size_t)(k0 + i) * 512 + n];
        *reinterpret_cast<uint4*>(w2p + (size_t)fl * 512 + lane * 8) = pack8(v);
    }
}

// ============ prepack_x1: R10 phase-1 (verbatim math) for 64 rows -> LDS, then copy to global ============
// x1p layout per 128-row block: [72 kt][4 mt32][1024 B]. prepack block bid covers mt32 {0,1} or {2,3}
// of fused block fb = bid>>1.
__global__ __launch_bounds__(1024, 4)
void prepack_x1(const float* __restrict__ x, const float* __restrict__ rot,
                const float* __restrict__ extra, char* __restrict__ x1p, int nrows) {
    __shared__ __align__(16) unsigned short buf[72 * 2 * 512];
    const int tid  = threadIdx.x;
    const int bid  = blockIdx.x;
    const int row0 = bid * 64;
    {
        const int m    = tid >> 4;
        const int l16  = tid & 15;
        const int mt32 = m >> 5;
        const int f0   = l16 * 8;
        int i = row0 + m; if (i > nrows - 1) i = nrows - 1;

        const float* xp = x + (size_t)i * 512 + f0;
        const float* ep = extra + (size_t)i * 512 + l16 * 32;
        f32x4 xl[8], el[8];
#pragma unroll
        for (int c = 0; c < 4; ++c) {
            xl[2 * c]     = *reinterpret_cast<const f32x4*>(xp + c * 128);
            xl[2 * c + 1] = *reinterpret_cast<const f32x4*>(xp + c * 128 + 4);
        }
#pragma unroll
        for (int q = 0; q < 8; ++q)
            el[q] = *reinterpret_cast<const f32x4*>(ep + q * 4);

        float r[9];
#pragma unroll
        for (int q = 0; q < 9; ++q) r[q] = rot[(size_t)i * 9 + q];

        auto stw = [&](int k0v, uint4 pv) {
            *reinterpret_cast<uint4*>(buf + ((k0v >> 4) * 2 + mt32) * 512 +
                                      ((m & 31) + 32 * ((k0v >> 3) & 1)) * 8) = pv;
        };

        stw(f0, pack8v(xl[0], xl[1]));
#pragma unroll
        for (int kk = 0; kk < 3; ++kk) {
            float vl[8];
#pragma unroll
            for (int j = 0; j < 8; ++j) {
                const float a = xl[2 + (j >> 2)][j & 3], b = xl[4 + (j >> 2)][j & 3], c = xl[6 + (j >> 2)][j & 3];
                vl[j] = a * r[kk] + b * r[3 + kk] + c * r[6 + kk];
            }
            stw(128 + kk * 128 + f0, pack8(vl));
        }
        {
            float nv[8];
#pragma unroll
            for (int j = 0; j < 8; ++j) {
                const float a = xl[2 + (j >> 2)][j & 3], b = xl[4 + (j >> 2)][j & 3], c = xl[6 + (j >> 2)][j & 3];
                nv[j] = sqrtf(a * a + b * b + c * c + EPS_C);
            }
            stw(512 + f0, pack8(nv));
        }
#pragma unroll
        for (int q = 0; q < 4; ++q)
            stw(640 + l16 * 32 + q * 8, pack8v(el[2 * q], el[2 * q + 1]));
    }
    __syncthreads();
    // copy 147456 B to global in [72 kt][4 mt] frag order
    const int fb  = bid >> 1;
    const int mtb = (bid & 1) * 2;
    const uint4* src = reinterpret_cast<const uint4*>(buf);
    uint4* dst = reinterpret_cast<uint4*>(x1p + (size_t)fb * 294912);
#pragma unroll
    for (int c = 0; c < 9; ++c) {
        const int idx = c * 1024 + tid;       // 0..9215
        const int lf  = idx >> 6;             // local frag [kt][2]
        const int win = idx & 63;
        const int kt  = lf >> 1;
        const int mt  = lf & 1;
        dst[(kt * 4 + mtb + mt) * 64 + win] = src[idx];
    }
}

// ===================== fused BM=128: DMA x1 panels, 2-N-pass GEMM1, h round-trip, GEMM2 =====================
__global__ __launch_bounds__(1024, 4)
void fused128_kernel(const float* __restrict__ rot,
                     const float* __restrict__ b1, const float* __restrict__ b2,
                     const char* __restrict__ w1pc, const bf16x8* __restrict__ w2p,
                     const char* __restrict__ x1p,
                     char* __restrict__ hmain, char* __restrict__ hspill,
                     long long out_bytes, float* __restrict__ out, int nrows) {
    // pool: panels dbuf 2 x 16384 ushorts (kt-local [8][4 mt][512]) | stg 32768 ushorts (GELU half-dump)
    __shared__ __align__(16) unsigned short pool[65536];   // 131072 B
    __shared__ float R_s[128 * 9];

    const int tid  = threadIdx.x;
    const int bid  = blockIdx.x;
    const int row0 = bid * 128;
    const int w    = tid >> 6;
    const int lane = tid & 63;
    const int l31  = lane & 31;

    char* hb = (((long long)(bid + 1) * 262144) <= out_bytes)
             ? (hmain + (size_t)bid * 262144) : hspill;
    const char* xb = x1p + (size_t)bid * 294912;

    unsigned short* const stg = pool + 32768;
    unsigned short* const Pb  = pool + 32768;   // GEMM2 DMA bufs (reuse stg area, lifetime-disjoint)

    // panel DMA: panel P = kt [8P, 8P+8), 32 KB, 32 chunks of 1 KB
    auto DMAP = [&](int P, int b01) {
#pragma unroll
        for (int c = 0; c < 2; ++c) {
            const int chunk = w * 2 + c;
            __builtin_amdgcn_global_load_lds(
                (const __attribute__((address_space(1))) unsigned int*)(xb + (size_t)P * 32768 + chunk * 1024 + lane * 16),
                (__attribute__((address_space(3))) unsigned int*)(pool + b01 * 16384 + chunk * 512),
                16, 0, 0);
        }
    };

    DMAP(0, 0);
    for (int t = tid; t < 128 * 9; t += 1024) {
        int idx = row0 * 9 + t;
        if (idx > nrows * 9 - 1) idx = nrows * 9 - 1;
        R_s[t] = rot[idx];
    }
    __syncthreads();   // panel 0 + R_s ready

    const int hi5 = lane >> 5;
    const int cz  = l31 >> 3;
    const int i7  = lane & 7;

    int gp = 0;   // global panel counter (0..17)
    for (int p = 0; p < 2; ++p) {
        const int t   = p * 16 + w;              // n-tile (32 cols)
        const float bw1 = b1[t * 32 + l31];

        f32x16 a0, a1, a2, a3;
#pragma unroll
        for (int z = 0; z < 16; ++z) { a0[z] = 0.f; a1[z] = 0.f; a2[z] = 0.f; a3[z] = 0.f; }

        auto LB1 = [&](int kt) {
            return *reinterpret_cast<const bf16x8*>(w1pc + ((size_t)(kt * 32 + t)) * 1024 + lane * 16);
        };
        auto MM = [&](const bf16x8 B, int pb, int ktl) {
            const unsigned short* ap = pool + pb * 16384 + ktl * 2048 + lane * 8;
            const bf16x8 A0 = *reinterpret_cast<const bf16x8*>(ap);
            const bf16x8 A1 = *reinterpret_cast<const bf16x8*>(ap + 512);
            const bf16x8 A2 = *reinterpret_cast<const bf16x8*>(ap + 1024);
            const bf16x8 A3 = *reinterpret_cast<const bf16x8*>(ap + 1536);
            __builtin_amdgcn_s_setprio(1);
            a0 = MFMA32(A0, B, a0);
            a1 = MFMA32(A1, B, a1);
            a2 = MFMA32(A2, B, a2);
            a3 = MFMA32(A3, B, a3);
            __builtin_amdgcn_s_setprio(0);
        };

        bf16x8 Ba = LB1(0), Bb;
        for (int ps = 0; ps < 9; ++ps, ++gp) {
            const int pb = gp & 1;
            if (gp + 1 < 18) DMAP((ps == 8) ? 0 : ps + 1, pb ^ 1);
#pragma unroll
            for (int ki = 0; ki < 8; ki += 2) {
                const int kt = ps * 8 + ki;
                Bb = LB1(kt + 1);
                MM(Ba, pb, ki);
                if (kt + 2 < 72) Ba = LB1(kt + 2);
                MM(Bb, pb, ki + 1);
            }
            __syncthreads();   // next panel's DMA drained; panel pb free for overwrite
        }

        // ---- bias + GELU -> stg (two 64 KB sub-rounds) -> global h ----
        auto GELF = [&](const f32x16& A, int msubBase) {
#pragma unroll
            for (int q = 0; q < 8; ++q) {
                const int reg  = 2 * q;
                const int msub = msubBase + (reg >> 3);             // 0..3
                const int rlo  = (reg & 3) + 8 * ((reg >> 2) & 1) + 4 * hi5;
                const unsigned pr = cvtpk(gelu_f(A[reg] + bw1), gelu_f(A[reg + 1] + bw1));
                unsigned short* pp = stg + (w * 4 + msub) * 512 + (rlo + 16 * cz) * 8 + i7;
                pp[0] = (unsigned short)pr;
                pp[8] = (unsigned short)(pr >> 16);
            }
        };
#pragma unroll
        for (int s = 0; s < 2; ++s) {
            if (s == 0) { GELF(a0, 0); GELF(a1, 2); }
            else        { GELF(a2, 0); GELF(a3, 2); }
            __syncthreads();
            // copy stg (64 KB) -> hb, frag (kt2 = p*16 + wof, mt16 = s*4 + mloc)
            const uint4* su = reinterpret_cast<const uint4*>(stg);
            uint4* du = reinterpret_cast<uint4*>(hb);
#pragma unroll
            for (int c = 0; c < 4; ++c) {
                const int idx   = c * 1024 + tid;   // 0..4095
                const int sfrag = idx >> 6;
                const int win   = idx & 63;
                const int wof   = sfrag >> 2;
                const int mloc  = sfrag & 3;
                du[((p * 16 + wof) * 8 + s * 4 + mloc) * 64 + win] = su[idx];
            }
            __syncthreads();
        }
    }

    // ================= GEMM2 (16x16x32): h from global DMA; wave (rh = w>>3, g2 = w&7) =================
    const int rh = w >> 3;
    const int g2 = w & 7;
    const int lr = lane & 15;
    const int lk = lane >> 4;

    f32x4 acc2[4][4];
#pragma unroll
    for (int mtl = 0; mtl < 4; ++mtl)
#pragma unroll
        for (int q = 0; q < 4; ++q) acc2[mtl][q] = (f32x4){0.f, 0.f, 0.f, 0.f};

    {
        const bf16x8* wb2 = w2p + (size_t)g2 * 64 + lane;
        auto LB2 = [&](bf16x8 (&C)[4], int kt2) {
#pragma unroll
            for (int q = 0; q < 4; ++q) C[q] = wb2[(size_t)kt2 * 2048 + q * 512];
        };
        auto DMA2 = [&](int k2) {
            __builtin_amdgcn_global_load_lds(
                (const __attribute__((address_space(1))) unsigned int*)(hb + k2 * 8192 + w * 1024 + lane * 16),
                (__attribute__((address_space(3))) unsigned int*)(Pb + (k2 & 1) * 4096 + w * 512),
                16, 0, 0);
        };
        auto STEP = [&](bf16x8 (&Cc)[4], bf16x8 (&Cn)[4], int kt2) {
            if (kt2 + 1 < 32) {
                if (w < 8) DMA2(kt2 + 1);
                LB2(Cn, kt2 + 1);
            }
            const unsigned short* ab = Pb + (kt2 & 1) * 4096 + (rh * 4) * 512 + lane * 8;
            __builtin_amdgcn_s_setprio(1);
#pragma unroll
            for (int mtl = 0; mtl < 4; ++mtl) {
                const bf16x8 A = *reinterpret_cast<const bf16x8*>(ab + mtl * 512);
#pragma unroll
                for (int q = 0; q < 4; ++q)
                    acc2[mtl][q] = MFMA16(A, Cc[q], acc2[mtl][q]);
            }
            __builtin_amdgcn_s_setprio(0);
            if (kt2 < 31) __syncthreads();
        };

        bf16x8 C0[4], C1[4];
        LB2(C0, 0);
        if (w < 8) DMA2(0);
        __syncthreads();
#pragma unroll
        for (int k2 = 0; k2 < 32; k2 += 2) {
            STEP(C0, C1, k2);
            STEP(C1, C0, k2 + 1);
        }
    }

    // ================= epilogue: in-register rotation + store =================
    {
        float bv2[4];
#pragma unroll
        for (int q = 0; q < 4; ++q) bv2[q] = b2[q * 128 + g2 * 16 + lr];
        const int fcol = g2 * 16 + lr;
#pragma unroll
        for (int mtl = 0; mtl < 4; ++mtl) {
#pragma unroll
            for (int j = 0; j < 4; ++j) {
                const int rl = rh * 64 + mtl * 16 + lk * 4 + j;
                if (row0 + rl < nrows) {
                    const float* Rp = R_s + rl * 9;
                    const float y0 = acc2[mtl][0][j] + bv2[0];
                    const float y1 = acc2[mtl][1][j] + bv2[1];
                    const float y2 = acc2[mtl][2][j] + bv2[2];
                    const float y3 = acc2[mtl][3][j] + bv2[3];
                    float* op = out + (size_t)(row0 + rl) * 512 + fcol;
                    op[0]   = y0;
                    op[128] = Rp[0] * y1 + Rp[1] * y2 + Rp[2] * y3;
                    op[256] = Rp[3] * y1 + Rp[4] * y2 + Rp[5] * y3;
                    op[384] = Rp[6] * y1 + Rp[7] * y2 + Rp[8] * y3;
                }
            }
        }
    }
}

// ===================== fallback: round-10 verified fused kernel (BM=64) =====================
__global__ __launch_bounds__(1024, 4)
void fused64_kernel(const float* __restrict__ x, const float* __restrict__ rot,
                    const float* __restrict__ extra,
                    const float* __restrict__ b1, const float* __restrict__ b2,
                    const char* __restrict__ w1pc, const bf16x8* __restrict__ w2p,
                    float* __restrict__ out, int nrows) {
    __shared__ __align__(16) unsigned short buf[72 * 2 * 512];
    __shared__ float R_s[64 * 9];

    const int tid  = threadIdx.x;
    const int row0 = blockIdx.x * 64;
    const int w    = tid >> 6;
    const int lane = tid & 63;

    {
        const int m    = tid >> 4;
        const int l16  = tid & 15;
        const int mt32 = m >> 5;
        const int f0   = l16 * 8;
        int i = row0 + m; if (i > nrows - 1) i = nrows - 1;
        const float* xp = x + (size_t)i * 512 + f0;
        const float* ep = extra + (size_t)i * 512 + l16 * 32;
        f32x4 xl[8], el[8];
#pragma unroll
        for (int c = 0; c < 4; ++c) {
            xl[2 * c]     = *reinterpret_cast<const f32x4*>(xp + c * 128);
            xl[2 * c + 1] = *reinterpret_cast<const f32x4*>(xp + c * 128 + 4);
        }
#pragma unroll
        for (int q = 0; q < 8; ++q)
            el[q] = *reinterpret_cast<const f32x4*>(ep + q * 4);
        float r[9];
#pragma unroll
        for (int q = 0; q < 9; ++q) r[q] = rot[(size_t)i * 9 + q];
        if (l16 < 9) R_s[m * 9 + l16] = r[l16];
        auto stw = [&](int k0v, uint4 pv) {
            *reinterpret_cast<uint4*>(buf + ((k0v >> 4) * 2 + mt32) * 512 +
                                      ((m & 31) + 32 * ((k0v >> 3) & 1)) * 8) = pv;
        };
        stw(f0, pack8v(xl[0], xl[1]));
#pragma unroll
        for (int kk = 0; kk < 3; ++kk) {
            float vl[8];
#pragma unroll
            for (int j = 0; j < 8; ++j) {
                const float a = xl[2 + (j >> 2)][j & 3], b = xl[4 + (j >> 2)][j & 3], c = xl[6 + (j >> 2)][j & 3];
                vl[j] = a * r[kk] + b * r[3 + kk] + c * r[6 + kk];
            }
            stw(128 + kk * 128 + f0, pack8(vl));
        }
        {
            float nv[8];
#pragma unroll
            for (int j = 0; j < 8; ++j) {
                const float a = xl[2 + (j >> 2)][j & 3], b = xl[4 + (j >> 2)][j & 3], c = xl[6 + (j >> 2)][j & 3];
                nv[j] = sqrtf(a * a + b * b + c * c + EPS_C);
            }
            stw(512 + f0, pack8(nv));
        }
#pragma unroll
        for (int q = 0; q < 4; ++q)
            stw(640 + l16 * 32 + q * 8, pack8v(el[2 * q], el[2 * q + 1]));
    }
    __syncthreads();

    const float bw1a = b1[(2 * w)     * 32 + (lane & 31)];
    const float bw1b = b1[(2 * w + 1) * 32 + (lane & 31)];

    f32x16 acc00, acc01, acc10, acc11;
#pragma unroll
    for (int z = 0; z < 16; ++z) { acc00[z] = 0.f; acc01[z] = 0.f; acc10[z] = 0.f; acc11[z] = 0.f; }

    {
        const char* wbase = w1pc + ((size_t)(2 * w) * 1024) + lane * 16;
        auto LB = [&](bf16x8& B0, bf16x8& B1, int kt) {
            B0 = *reinterpret_cast<const bf16x8*>(wbase + (size_t)kt * 32768);
            B1 = *reinterpret_cast<const bf16x8*>(wbase + (size_t)kt * 32768 + 1024);
        };
        auto MM = [&](const bf16x8 B0, const bf16x8 B1, int kt) {
            const unsigned short* ap = buf + kt * 1024 + lane * 8;
            const bf16x8 A0 = *reinterpret_cast<const bf16x8*>(ap);
            const bf16x8 A1 = *reinterpret_cast<const bf16x8*>(ap + 512);
            __builtin_amdgcn_s_setprio(1);
            acc00 = MFMA32(A0, B0, acc00);
            acc01 = MFMA32(A0, B1, acc01);
            acc10 = MFMA32(A1, B0, acc10);
            acc11 = MFMA32(A1, B1, acc11);
            __builtin_amdgcn_s_setprio(0);
        };
        bf16x8 Ba0, Ba1, Bb0, Bb1, Bc0, Bc1;
        LB(Ba0, Ba1, 0); LB(Bb0, Bb1, 1);
#pragma unroll
        for (int kt = 0; kt < 72; kt += 3) {
            LB(Bc0, Bc1, kt + 2);
            MM(Ba0, Ba1, kt);
            if (kt + 3 < 72) LB(Ba0, Ba1, kt + 3);
            MM(Bb0, Bb1, kt + 1);
            if (kt + 4 < 72) LB(Bb0, Bb1, kt + 4);
            MM(Bc0, Bc1, kt + 2);
        }
    }
    __syncthreads();

    {
        const int hi5 = lane >> 5;
        const int cz  = (lane & 31) >> 3;
        const int i7  = lane & 7;
        auto GEL = [&](const f32x16& A, int mtl, int ntl, float bb) {
            const int ktn = 2 * w + ntl;
#pragma unroll
            for (int q = 0; q < 8; ++q) {
                const int reg  = 2 * q;
                const int mt16 = mtl * 2 + (reg >> 3);
                const int rlo  = (reg & 3) + 8 * ((reg >> 2) & 1) + 4 * hi5;
                const unsigned pr = cvtpk(gelu_f(A[reg] + bb), gelu_f(A[reg + 1] + bb));
                unsigned short* p = &buf[(ktn * 4 + mt16) * 512 + (rlo + 16 * cz) * 8 + i7];
                p[0] = (unsigned short)pr;
                p[8] = (unsigned short)(pr >> 16);
            }
        };
        GEL(acc00, 0, 0, bw1a);
        GEL(acc01, 0, 1, bw1b);
        GEL(acc10, 1, 0, bw1a);
        GEL(acc11, 1, 1, bw1b);
    }
    __syncthreads();

    const int mh = w >> 3;
    const int g  = w & 7;
    const int lr = lane & 15;
    const int lk = lane >> 4;

    f32x4 acc2[2][4];
#pragma unroll
    for (int mtl = 0; mtl < 2; ++mtl)
#pragma unroll
        for (int p = 0; p < 4; ++p) acc2[mtl][p] = (f32x4){0.f, 0.f, 0.f, 0.f};

    {
        const bf16x8* wb2 = w2p + (size_t)g * 64 + lane;
        auto LB2 = [&](bf16x8* C, int kt2) {
#pragma unroll
            for (int p = 0; p < 4; ++p) C[p] = wb2[(size_t)kt2 * 2048 + p * 512];
        };
        auto MM2 = [&](const bf16x8* C, int kt2) {
            const unsigned short* ab = buf + kt2 * 2048 + (mh * 2) * 512 + lane * 8;
            const bf16x8 a0 = *reinterpret_cast<const bf16x8*>(ab);
            const bf16x8 a1 = *reinterpret_cast<const bf16x8*>(ab + 512);
            __builtin_amdgcn_s_setprio(1);
#pragma unroll
            for (int p = 0; p < 4; ++p) {
                acc2[0][p] = MFMA16(a0, C[p], acc2[0][p]);
                acc2[1][p] = MFMA16(a1, C[p], acc2[1][p]);
            }
            __builtin_amdgcn_s_setprio(0);
        };
        bf16x8 Ca[4], Cb[4];
        LB2(Ca, 0);
#pragma unroll
        for (int kt2 = 0; kt2 < 32; kt2 += 2) {
            if (kt2 + 1 < 32) LB2(Cb, kt2 + 1);
            MM2(Ca, kt2);
            if (kt2 + 2 < 32) LB2(Ca, kt2 + 2);
            if (kt2 + 1 < 32) MM2(Cb, kt2 + 1);
        }
    }

    {
        float bv2[4];
#pragma unroll
        for (int p = 0; p < 4; ++p) bv2[p] = b2[p * 128 + g * 16 + lr];
        const int fcol = g * 16 + lr;
#pragma unroll
        for (int mtl = 0; mtl < 2; ++mtl) {
#pragma unroll
            for (int j = 0; j < 4; ++j) {
                const int rl = (mh * 2 + mtl) * 16 + lk * 4 + j;
                if (row0 + rl < nrows) {
                    const float* Rp = R_s + rl * 9;
                    const float y0 = acc2[mtl][0][j] + bv2[0];
                    const float y1 = acc2[mtl][1][j] + bv2[1];
                    const float y2 = acc2[mtl][2][j] + bv2[2];
                    const float y3 = acc2[mtl][3][j] + bv2[3];
                    float* op = out + (size_t)(row0 + rl) * 512 + fcol;
                    op[0]   = y0;
                    op[128] = Rp[0] * y1 + Rp[1] * y2 + Rp[2] * y3;
                    op[256] = Rp[3] * y1 + Rp[4] * y2 + Rp[5] * y3;
                    op[384] = Rp[6] * y1 + Rp[7] * y2 + Rp[8] * y3;
                }
            }
        }
    }
}

extern "C" void kernel_launch(void* const* d_in, const int* in_sizes, int n_in,
                              void* d_out, int out_size, void* d_ws, size_t ws_size,
                              hipStream_t stream) {
    const float* x     = (const float*)d_in[0];
    const float* rot   = (const float*)d_in[1];
    const float* extra = (const float*)d_in[2];
    const float* W1    = (const float*)d_in[3];
    const float* b1    = (const float*)d_in[4];
    const float* W2    = (const float*)d_in[5];
    const float* b2    = (const float*)d_in[6];
    float* out = (float*)d_out;

    const int nrows = in_sizes[0] / 512;

    unsigned short* w1p = (unsigned short*)d_ws;
    unsigned short* w2p = (unsigned short*)((char*)d_ws + (size_t)2304 * 1024);

    prep_kernel<<<(3328 * 64 + 255) / 256, 256, 0, stream>>>(W1, W2, w1p, w2p);

    const int nblk128 = (nrows + 127) / 128;
    const size_t x1pOff   = (size_t)3328 * 1024;
    const size_t x1pBytes = (size_t)nblk128 * 294912;
    const size_t need     = x1pOff + x1pBytes + 262144;

    if (ws_size >= need) {
        char* x1p    = (char*)d_ws + x1pOff;
        char* hspill = x1p + x1pBytes;
        const long long out_bytes = (long long)out_size * 4;
        prepack_x1<<<nblk128 * 2, 1024, 0, stream>>>(x, rot, extra, x1p, nrows);
        fused128_kernel<<<nblk128, 1024, 0, stream>>>(rot, b1, b2,
                                                      (const char*)w1p, (const bf16x8*)w2p,
                                                      (const char*)x1p,
                                                      (char*)d_out, hspill, out_bytes,
                                                      out, nrows);
    } else {
        const int nblk64 = (nrows + 63) / 64;
        fused64_kernel<<<nblk64, 1024, 0, stream>>>(x, rot, extra, b1, b2,
                                                    (const char*)w1p, (const bf16x8*)w2p,
                                                    out, nrows);
    }
}